// Round 2
// baseline (452.280 us; speedup 1.0000x reference)
//
#include <hip/hip_runtime.h>

typedef unsigned short u16;
typedef __attribute__((ext_vector_type(8))) short bf16x8;   // 8 x bf16 (4 VGPRs)
typedef __attribute__((ext_vector_type(4))) float f32x4;

#define NLEV 5
#define CCH 256
#define KTOT 2304            // 9 taps * 256 ci
#define P_TOT 8525           // sum HW
#define PP_TOT 9165          // sum (H+2)*(W+2)

__constant__ int   c_HW[NLEV]     = {6400, 1600, 400, 100, 25};
__constant__ int   c_W[NLEV]      = {80, 40, 20, 10, 5};
__constant__ int   c_off[NLEV]    = {0, 6400, 8000, 8400, 8500};
__constant__ int   c_poff[NLEV]   = {0, 6724, 8488, 8972, 9116};
__constant__ int   c_pts[NLEV+1]  = {0, 100, 125, 132, 134, 135};   // ptile starts, BN=64
__constant__ float c_stridef[NLEV]= {8.f, 16.f, 32.f, 64.f, 128.f};

__device__ __forceinline__ u16 f2bf(float f){
  union { float f; unsigned u; } v; v.f = f;
  unsigned r = v.u + 0x7fffu + ((v.u >> 16) & 1u);   // RNE
  return (u16)(r >> 16);
}

// async global->LDS: each lane contributes 16B; LDS dst is wave-uniform base,
// HW scatters lane i to base + i*16.
__device__ __forceinline__ void g2l16(const u16* g, u16* l, int lane){
#if defined(__has_builtin)
#if __has_builtin(__builtin_amdgcn_global_load_lds)
  __builtin_amdgcn_global_load_lds(
      (const __attribute__((address_space(1))) unsigned int*)g,
      (__attribute__((address_space(3))) unsigned int*)l, 16, 0, 0);
  return;
#endif
#endif
  *(uint4*)(l + lane*8) = *(const uint4*)g;  // fallback: sync copy
}

// ---------------------------------------------------------------------------
// Implicit-GEMM conv 3x3, padded NHWC bf16 input, split-K x2.
// blockIdx.z = kh*2 + branch (kh = K-half, branch = cls/box).
// Tile BM=128 x BN=64 x BK=64 (18 stages of 64k; 16 MFMA per barrier pair).
// LDS rows are 128B with XOR-16B-granule swizzle: logical granule g of row r
// lives at phys g^(r&7). Staged by permuting the SOURCE k-offset per lane
// (global_load_lds writes lane-ordered), read back with swizzled ds_read_b128
// -> 2-way bank aliasing only (free).
// MODE 0: tower conv (M=256) -> Y fp32 [pixel][256] partial (no bias)
// MODE 1: heads (branch0: score 80 rows; branch1: pred 4 + iou 1, padded 128)
//         -> OP fp32 [branch*2+kh][pixel][128] raw partials
// ---------------------------------------------------------------------------
template<int MODE>
__global__ __launch_bounds__(256, 4) void gemm_conv(
    const u16* __restrict__ Xc, const u16* __restrict__ Xb,
    const u16* __restrict__ Wc, const u16* __restrict__ Wb,
    float* __restrict__ Y0c, float* __restrict__ Y1c,
    float* __restrict__ Y0b, float* __restrict__ Y1b,
    float* __restrict__ OP)
{
  __shared__ u16 sA[128*64];   // [m][64k], 128B rows, swizzled
  __shared__ u16 sB[64*64];    // [n][64k]

  const int ptile = blockIdx.x, mtile = blockIdx.y;
  const int kh = blockIdx.z >> 1, br = blockIdx.z & 1;
  int lv = 0;
  #pragma unroll
  for (int i = 1; i < NLEV; i++) if (ptile >= c_pts[i]) lv = i;
  const int ptl = ptile - c_pts[lv];
  const int HW = c_HW[lv], Wl = c_W[lv], wrow = Wl + 2;
  const int tid = threadIdx.x, wv = tid >> 6, ln = tid & 63;
  const int quad = ln >> 4, l15 = ln & 15;
  const int lr = ln >> 3;                 // row within an 8-row staging call
  const int gsw = (ln & 7) ^ lr;          // swizzled source granule (16B units)

  const u16* X  = br ? Xb : Xc;
  const u16* WA = br ? Wb : Wc;

  // A staging: 4 calls/wave, rows mtile*128 + wv*32 + j*8 + lr
  const u16* abase = WA + (size_t)(mtile*128 + wv*32 + lr) * KTOT + gsw*8;
  u16* adst = &sA[(wv*32) * 64];

  // B staging: 2 calls/wave, pixel rows ptl*64 + wv*16 + j*8 + lr
  const u16* bptr[2];
  #pragma unroll
  for (int j = 0; j < 2; j++) {
    const int p = ptl*64 + wv*16 + j*8 + lr;
    int pb = 0;
    if (p < HW) { int h = p / Wl; int wi = p - h*Wl; pb = h*wrow + wi; }
    bptr[j] = X + (size_t)(c_poff[lv] + pb) * CCH + gsw*8;
  }
  u16* bdst = &sB[(wv*16) * 64];

  f32x4 acc[2][4];
  #pragma unroll
  for (int i = 0; i < 2; i++)
    #pragma unroll
    for (int j = 0; j < 4; j++) acc[i][j] = (f32x4){0.f, 0.f, 0.f, 0.f};

  const int s0 = kh * 18, s1 = s0 + 18;
  for (int s = s0; s < s1; s++) {
    const int tap = s >> 2;
    const int dh = tap / 3, dw = tap - dh*3;
    const u16* as = abase + (size_t)s * 64;
    g2l16(as,            adst,         ln);
    g2l16(as +  8*KTOT,  adst +  8*64, ln);
    g2l16(as + 16*KTOT,  adst + 16*64, ln);
    g2l16(as + 24*KTOT,  adst + 24*64, ln);
    const int bsh = (dh*wrow + dw)*CCH + ((s & 3) << 6);
    g2l16(bptr[0] + bsh, bdst,         ln);
    g2l16(bptr[1] + bsh, bdst +  8*64, ln);
    __syncthreads();
    bf16x8 af[2][2], bf[2][4];
    #pragma unroll
    for (int sub = 0; sub < 2; sub++) {
      const int gbase = (sub*4 + quad) ^ (l15 & 7);   // phys granule
      #pragma unroll
      for (int i = 0; i < 2; i++)
        af[sub][i] = *(const bf16x8*)&sA[(wv*32 + i*16 + l15)*64 + gbase*8];
      #pragma unroll
      for (int j = 0; j < 4; j++)
        bf[sub][j] = *(const bf16x8*)&sB[(j*16 + l15)*64 + gbase*8];
    }
    #pragma unroll
    for (int sub = 0; sub < 2; sub++)
      #pragma unroll
      for (int i = 0; i < 2; i++)
        #pragma unroll
        for (int j = 0; j < 4; j++)
          acc[i][j] = __builtin_amdgcn_mfma_f32_16x16x32_bf16(af[sub][i], bf[sub][j], acc[i][j], 0, 0, 0);
    __syncthreads();
  }

  const int nrem = HW - ptl*64;
  if (MODE == 0) {
    float* Y = br ? (kh ? Y1b : Y0b) : (kh ? Y1c : Y0c);
    #pragma unroll
    for (int mi = 0; mi < 2; mi++) {
      const int m0 = mtile*128 + wv*32 + mi*16 + quad*4;
      #pragma unroll
      for (int ni = 0; ni < 4; ni++) {
        const int nl = ni*16 + l15;
        if (nl < nrem) {
          const size_t n = (size_t)(c_off[lv] + ptl*64 + nl);
          *(f32x4*)&Y[n*CCH + m0] = acc[mi][ni];
        }
      }
    }
  } else {
    float* O = OP + (size_t)(br*2 + kh) * P_TOT * 128;
    #pragma unroll
    for (int mi = 0; mi < 2; mi++) {
      const int m0 = wv*32 + mi*16 + quad*4;
      #pragma unroll
      for (int ni = 0; ni < 4; ni++) {
        const int nl = ni*16 + l15;
        if (nl < nrem) {
          const size_t n = (size_t)(c_off[lv] + ptl*64 + nl);
          *(f32x4*)&O[n*128 + m0] = acc[mi][ni];
        }
      }
    }
  }
}

// GN stats: one block per (64-pixel slice, branch); thread = channel.
// v = Y0 + Y1 + bias; reduce sum/sumsq per 8-channel group -> global atomics.
__global__ __launch_bounds__(256) void gn_stats(
    const float* __restrict__ Y0c, const float* __restrict__ Y1c,
    const float* __restrict__ Y0b, const float* __restrict__ Y1b,
    const float* __restrict__ bc, const float* __restrict__ bb,
    float* __restrict__ stats)
{
  const int sl = blockIdx.x, br = blockIdx.y;
  int lv = 0;
  #pragma unroll
  for (int i = 1; i < NLEV; i++) if (sl >= c_pts[i]) lv = i;
  const int sll = sl - c_pts[lv];
  const int HW = c_HW[lv];
  const float* Y0 = br ? Y0b : Y0c;
  const float* Y1 = br ? Y1b : Y1c;
  const int c = threadIdx.x;
  const float b = (br ? bb : bc)[c];
  float s = 0.f, sq = 0.f;
  const int p0 = sll * 64;
  for (int i = 0; i < 64; i++) {
    const int p = p0 + i;
    if (p >= HW) break;
    const size_t idx = (size_t)(c_off[lv] + p) * CCH + c;
    const float v = Y0[idx] + Y1[idx] + b;
    s += v; sq += v*v;
  }
  s += __shfl_xor(s, 1); sq += __shfl_xor(sq, 1);
  s += __shfl_xor(s, 2); sq += __shfl_xor(sq, 2);
  s += __shfl_xor(s, 4); sq += __shfl_xor(sq, 4);
  if ((c & 7) == 0) {
    const int g = c >> 3;
    atomicAdd(&stats[((br*NLEV + lv)*32 + g)*2 + 0], s);
    atomicAdd(&stats[((br*NLEV + lv)*32 + g)*2 + 1], sq);
  }
}

// GN finalize + affine + ReLU + bf16 cast into padded NHWC (8 ch / thread)
__global__ __launch_bounds__(256) void gn_relu(
    const float* __restrict__ Y0c, const float* __restrict__ Y1c,
    const float* __restrict__ Y0b, const float* __restrict__ Y1b,
    const float* __restrict__ stats,
    const float* __restrict__ bc, const float* __restrict__ bb,
    const float* __restrict__ gwc, const float* __restrict__ gbc,
    const float* __restrict__ gwb, const float* __restrict__ gbb,
    u16* __restrict__ Xc, u16* __restrict__ Xb)
{
  const int t = blockIdx.x * 256 + threadIdx.x;
  if (t >= 2 * P_TOT * 32) return;
  const int br = t / (P_TOT * 32);
  const int r  = t - br * (P_TOT * 32);
  const int pg = r >> 5;
  const int c0 = (r & 31) << 3;
  int lv = 0;
  #pragma unroll
  for (int i = 1; i < NLEV; i++) if (pg >= c_off[i]) lv = i;
  const int pl = pg - c_off[lv];
  const int Wl = c_W[lv];
  const int g = c0 >> 3;
  const float* st = &stats[(((size_t)br*NLEV + lv)*32 + g)*2];
  const float cnt = 8.f * (float)c_HW[lv];
  const float mean = st[0] / cnt;
  const float var  = st[1] / cnt - mean*mean;
  const float rstd = rsqrtf(var + 1e-5f);
  const float* Y0 = br ? Y0b : Y0c;
  const float* Y1 = br ? Y1b : Y1c;
  const float* bs = br ? bb : bc;
  const float* gw = br ? gwb : gwc;
  const float* gb = br ? gbb : gbc;
  u16* X = br ? Xb : Xc;
  const float* y0 = &Y0[(size_t)pg*CCH + c0];
  const float* y1 = &Y1[(size_t)pg*CCH + c0];
  const int h = pl / Wl, wi = pl - h*Wl;
  const size_t pidx = (size_t)(c_poff[lv] + (h+1)*(Wl+2) + (wi+1));
  union { u16 u[8]; uint4 v; } pk;
  #pragma unroll
  for (int i = 0; i < 8; i++) {
    const float v = (y0[i] + y1[i] + bs[c0+i] - mean)*rstd*gw[c0+i] + gb[c0+i];
    pk.u[i] = f2bf(fmaxf(v, 0.f));
  }
  *(uint4*)&X[pidx*CCH + c0] = pk.v;
}

// Head epilogue: combine split-K partials + bias/scale/relu/stride -> out[n][85]
__global__ __launch_bounds__(256) void head_out(
    const float* __restrict__ OP,
    const float* __restrict__ score_b, const float* __restrict__ pred_b,
    const float* __restrict__ iou_b, const float* __restrict__ scales,
    float* __restrict__ out)
{
  const int t = blockIdx.x * 256 + threadIdx.x;
  if (t >= P_TOT * 96) return;
  const int n = t / 96, m = t - n*96;
  if (m >= 85) return;
  int lv = 0;
  #pragma unroll
  for (int i = 1; i < NLEV; i++) if (n >= c_off[i]) lv = i;
  const size_t S = (size_t)P_TOT * 128;
  const size_t r = (size_t)n * 128;
  if (m < 80) {
    out[(size_t)n*85 + m] = OP[r + m] + OP[S + r + m] + score_b[m];
  } else if (m < 84) {
    const int mm = m - 80;
    float v = (OP[2*S + r + mm] + OP[3*S + r + mm] + pred_b[mm]) * scales[lv];
    out[(size_t)n*85 + 80 + mm] = fmaxf(v, 0.f) * c_stridef[lv];
  } else {
    out[(size_t)n*85 + 84] = OP[2*S + r + 4] + OP[3*S + r + 4] + iou_b[0];
  }
}

// fp32 NCHW feats -> bf16 padded NHWC
__global__ __launch_bounds__(256) void feat2bf(
    const float* __restrict__ p3, const float* __restrict__ p4,
    const float* __restrict__ p5, const float* __restrict__ p6,
    const float* __restrict__ p7, u16* __restrict__ X)
{
  const int t = blockIdx.x * 256 + threadIdx.x;
  if (t >= P_TOT * 32) return;
  const int pg = t >> 5, c0 = (t & 31) << 3;
  int lv = 0;
  #pragma unroll
  for (int i = 1; i < NLEV; i++) if (pg >= c_off[i]) lv = i;
  const int pl = pg - c_off[lv];
  const float* src = lv==0 ? p3 : lv==1 ? p4 : lv==2 ? p5 : lv==3 ? p6 : p7;
  const int HW = c_HW[lv], Wl = c_W[lv];
  const int h = pl / Wl, wi = pl - h*Wl;
  const size_t pidx = (size_t)(c_poff[lv] + (h+1)*(Wl+2) + (wi+1));
  union { u16 u[8]; uint4 v; } pk;
  #pragma unroll
  for (int i = 0; i < 8; i++)
    pk.u[i] = f2bf(src[(size_t)(c0+i)*HW + pl]);
  *(uint4*)&X[pidx*CCH + c0] = pk.v;
}

// tower weights [l][co][ci][9] fp32 -> bf16 [l*256+co][tap*256+ci]
__global__ __launch_bounds__(256) void wconv(
    const float* __restrict__ cw, const float* __restrict__ bw,
    u16* __restrict__ Wc, u16* __restrict__ Wb)
{
  const size_t N = (size_t)4*256*KTOT;
  const size_t t = (size_t)blockIdx.x * 256 + threadIdx.x;
  if (t >= 2*N) return;
  const float* src = (t < N) ? cw : bw;
  u16* dst = (t < N) ? Wc : Wb;
  const size_t i = (t < N) ? t : t - N;
  const size_t lc = i / KTOT;
  const int kk = (int)(i - lc*KTOT);
  const int tap = kk >> 8, ci = kk & 255;
  dst[i] = f2bf(src[(lc*256 + ci)*9 + tap]);
}

// head weights -> bf16 [128 rows padded][tap*256+ci] (cls: 80 rows; box: 4 pred + 1 iou)
__global__ __launch_bounds__(256) void hconv(
    const float* __restrict__ sw, const float* __restrict__ pw,
    const float* __restrict__ iw, u16* __restrict__ Whc, u16* __restrict__ Whb)
{
  const int N = 128 * KTOT;
  const int t = blockIdx.x * 256 + threadIdx.x;
  if (t >= 2*N) return;
  const int i = (t < N) ? t : t - N;
  const int co = i / KTOT, kk = i - co*KTOT;
  const int tap = kk >> 8, ci = kk & 255;
  float v = 0.f;
  if (t < N) {
    if (co < 80) v = sw[(co*256 + ci)*9 + tap];
    Whc[i] = f2bf(v);
  } else {
    if (co < 4)       v = pw[(co*256 + ci)*9 + tap];
    else if (co == 4) v = iw[ci*9 + tap];
    Whb[i] = f2bf(v);
  }
}

extern "C" void kernel_launch(void* const* d_in, const int* in_sizes, int n_in,
                              void* d_out, int out_size, void* d_ws, size_t ws_size,
                              hipStream_t stream)
{
  const float* p3      = (const float*)d_in[0];
  const float* p4      = (const float*)d_in[1];
  const float* p5      = (const float*)d_in[2];
  const float* p6      = (const float*)d_in[3];
  const float* p7      = (const float*)d_in[4];
  const float* cls_w   = (const float*)d_in[5];
  const float* cls_b   = (const float*)d_in[6];
  const float* cls_gw  = (const float*)d_in[7];
  const float* cls_gb  = (const float*)d_in[8];
  const float* box_w   = (const float*)d_in[9];
  const float* box_b   = (const float*)d_in[10];
  const float* box_gw  = (const float*)d_in[11];
  const float* box_gb  = (const float*)d_in[12];
  const float* score_w = (const float*)d_in[13];
  const float* score_b = (const float*)d_in[14];
  const float* pred_w  = (const float*)d_in[15];
  const float* pred_b  = (const float*)d_in[16];
  const float* iou_w   = (const float*)d_in[17];
  const float* iou_b   = (const float*)d_in[18];
  const float* scales  = (const float*)d_in[19];
  float* out = (float*)d_out;

  char* w = (char*)d_ws;
  size_t o = 0;
  auto alloc = [&](size_t b) { void* p = w + o; o += (b + 255) & ~(size_t)255; return p; };
  u16* WRC = (u16*)alloc((size_t)4*256*KTOT*2);
  u16* WRB = (u16*)alloc((size_t)4*256*KTOT*2);
  u16* WHC = (u16*)alloc((size_t)128*KTOT*2);
  u16* WHB = (u16*)alloc((size_t)128*KTOT*2);
  u16* XF  = (u16*)alloc((size_t)PP_TOT*CCH*2);   // XF,XC,XB contiguous (256B multiples)
  u16* XC  = (u16*)alloc((size_t)PP_TOT*CCH*2);
  u16* XB  = (u16*)alloc((size_t)PP_TOT*CCH*2);
  float* Y0C = (float*)alloc((size_t)P_TOT*CCH*4);
  float* Y1C = (float*)alloc((size_t)P_TOT*CCH*4);
  float* Y0B = (float*)alloc((size_t)P_TOT*CCH*4);
  float* Y1B = (float*)alloc((size_t)P_TOT*CCH*4);
  float* OP  = (float*)alloc((size_t)4*P_TOT*128*4);
  float* ST  = (float*)alloc((size_t)2*NLEV*32*2*4);

  // zero padded activation buffers (borders must be 0)
  hipMemsetAsync(XF, 0, (size_t)3*PP_TOT*CCH*2, stream);

  wconv<<<dim3((unsigned)(((size_t)2*4*256*KTOT + 255)/256)), 256, 0, stream>>>(cls_w, box_w, WRC, WRB);
  hconv<<<dim3((2*128*KTOT + 255)/256), 256, 0, stream>>>(score_w, pred_w, iou_w, WHC, WHB);
  feat2bf<<<dim3((P_TOT*32 + 255)/256), 256, 0, stream>>>(p3, p4, p5, p6, p7, XF);

  const u16* xci = XF; const u16* xbi = XF;
  for (int l = 0; l < 4; l++) {
    hipMemsetAsync(ST, 0, (size_t)2*NLEV*32*2*4, stream);
    gemm_conv<0><<<dim3(135, 2, 4), 256, 0, stream>>>(
        xci, xbi, WRC + (size_t)l*256*KTOT, WRB + (size_t)l*256*KTOT,
        Y0C, Y1C, Y0B, Y1B, nullptr);
    gn_stats<<<dim3(135, 2), 256, 0, stream>>>(
        Y0C, Y1C, Y0B, Y1B, cls_b + l*256, box_b + l*256, ST);
    gn_relu<<<dim3((2*P_TOT*32 + 255)/256), 256, 0, stream>>>(
        Y0C, Y1C, Y0B, Y1B, ST, cls_b + l*256, box_b + l*256,
        cls_gw + l*256, cls_gb + l*256, box_gw + l*256, box_gb + l*256,
        XC, XB);
    xci = XC; xbi = XB;
  }
  gemm_conv<1><<<dim3(135, 1, 4), 256, 0, stream>>>(
      xci, xbi, WHC, WHB, nullptr, nullptr, nullptr, nullptr, OP);
  head_out<<<dim3((P_TOT*96 + 255)/256), 256, 0, stream>>>(
      OP, score_b, pred_b, iou_b, scales, out);
}